// Round 4
// baseline (307.193 us; speedup 1.0000x reference)
//
#include <hip/hip_runtime.h>

typedef __bf16 bf16x8 __attribute__((ext_vector_type(8)));
typedef float f32x4 __attribute__((ext_vector_type(4)));
typedef unsigned int u32x4 __attribute__((ext_vector_type(4)));

typedef const void __attribute__((address_space(1)))* gas1;
typedef void __attribute__((address_space(3)))* las3;

__device__ __forceinline__ unsigned short f2bf(float f) {
  unsigned int u = __builtin_bit_cast(unsigned int, f);
  u += 0x7fffu + ((u >> 16) & 1u);   // RNE
  return (unsigned short)(u >> 16);
}
__device__ __forceinline__ float bf2f(unsigned short h) {
  unsigned int u = ((unsigned int)h) << 16;
  return __builtin_bit_cast(float, u);
}
__device__ __forceinline__ unsigned int pack2bf(float lo, float hi) {
  return (unsigned int)f2bf(lo) | ((unsigned int)f2bf(hi) << 16);
}
// truncating pack (P in [0,1])
__device__ __forceinline__ unsigned int packtr(float lo, float hi) {
  return __builtin_amdgcn_perm(__builtin_bit_cast(unsigned int, hi),
                               __builtin_bit_cast(unsigned int, lo), 0x07060302u);
}

// ---------------- fused prep: x->bf16 + 4 weight transposes + packed sin/cos ----------
__global__ __launch_bounds__(256) void prep(const float* __restrict__ x,
                                            const float* __restrict__ wq,
                                            const float* __restrict__ wk,
                                            const float* __restrict__ wv,
                                            const float* __restrict__ wo,
                                            const float* __restrict__ sinT,
                                            const float* __restrict__ cosT,
                                            unsigned short* __restrict__ xb,
                                            unsigned short* __restrict__ wtqkv,
                                            unsigned short* __restrict__ wot,
                                            float2* __restrict__ scT) {
  __shared__ float tile[32][33];
  const int b = blockIdx.x;
  const int tid = threadIdx.x;
  if (b < 4096) {
    int i = b * 256 + tid;
    float4 v = ((const float4*)x)[i];
    uint2 o;
    o.x = pack2bf(v.x, v.y);
    o.y = pack2bf(v.z, v.w);
    ((uint2*)xb)[i] = o;
    return;
  }
  if (b >= 6656) {
    int idx = (b - 6656) * 256 + tid;    // 131072 = 4096*32
    scT[idx] = make_float2(sinT[idx], cosT[idx]);
    return;
  }
  const float* src;
  unsigned short* dst;
  int R, C, t;
  if (b < 5120)      { t = b - 4096; src = wq; dst = wtqkv;               R = 1024; C = 1024; }
  else if (b < 5376) { t = b - 5120; src = wk; dst = wtqkv + 1024 * 1024; R = 1024; C = 256; }
  else if (b < 5632) { t = b - 5376; src = wv; dst = wtqkv + 1280 * 1024; R = 1024; C = 256; }
  else               { t = b - 5632; src = wo; dst = wot;                 R = 1024; C = 1024; }
  const int ntc = C >> 5;
  const int c0 = (t % ntc) * 32, r0 = (t / ntc) * 32;
  const int tx = tid & 31, ty = tid >> 5;
#pragma unroll
  for (int i = 0; i < 4; ++i)
    tile[ty + i * 8][tx] = src[(r0 + ty + i * 8) * C + c0 + tx];
  __syncthreads();
#pragma unroll
  for (int i = 0; i < 4; ++i)
    dst[(c0 + ty + i * 8) * R + r0 + tx] = f2bf(tile[tx][ty + i * 8]);
}

// ======================================================================
// 128x128-tile, 4-wave, BK=64, double-buffered GEMM core (unchanged).
// ======================================================================

__device__ __forceinline__ void stage_tile(const unsigned short* __restrict__ src,
                                           unsigned short* lds, int tid) {
  const int w = tid >> 6;            // wave id (0..3)
  const int l = tid & 63;
  const int rsub = l >> 3;           // 0..7 row within 8-row group
  const int cblk = l & 7;            // 0..7 16B block within row
#pragma unroll
  for (int i = 0; i < 4; ++i) {
    const int row = i * 32 + w * 8 + rsub;
    const int scol = (cblk ^ (row & 7)) * 8;   // pre-swizzled source column
    __builtin_amdgcn_global_load_lds((gas1)(const void*)&src[(size_t)row * 1024 + scol],
                                     (las3)(void*)&lds[(i * 32 + w * 8) * 64], 16, 0, 0);
  }
}

#define GEMM_STEP(CUR, NXT, KNEXT, DO_STAGE)                                          \
  {                                                                                   \
    if (DO_STAGE) {                                                                   \
      stage_tile(Ab + (KNEXT), sm[NXT][0], tid);                                      \
      stage_tile(Bb + (KNEXT), sm[NXT][1], tid);                                      \
    }                                                                                 \
    const char* As = (const char*)sm[CUR][0];                                         \
    const char* Bs = (const char*)sm[CUR][1];                                         \
    bf16x8 af[2][4], bfr[2][4];                                                       \
    _Pragma("unroll")                                                                 \
    for (int kk = 0; kk < 2; ++kk) {                                                  \
      const int co = (kk * 64 + lgrp * 16) ^ xorsel;                                  \
      _Pragma("unroll")                                                               \
      for (int mi = 0; mi < 4; ++mi)                                                  \
        af[kk][mi] = __builtin_bit_cast(bf16x8,                                       \
            *(const u32x4*)(As + arow + mi * 2048 + co));                             \
      _Pragma("unroll")                                                               \
      for (int ni = 0; ni < 4; ++ni)                                                  \
        bfr[kk][ni] = __builtin_bit_cast(bf16x8,                                      \
            *(const u32x4*)(Bs + brow + ni * 2048 + co));                             \
    }                                                                                 \
    _Pragma("unroll")                                                                 \
    for (int kk = 0; kk < 2; ++kk)                                                    \
      _Pragma("unroll")                                                               \
      for (int mi = 0; mi < 4; ++mi)                                                  \
        _Pragma("unroll")                                                             \
        for (int ni = 0; ni < 4; ++ni)                                                \
          acc[mi][ni] = __builtin_amdgcn_mfma_f32_16x16x32_bf16(af[kk][mi],           \
                            bfr[kk][ni], acc[mi][ni], 0, 0, 0);                       \
    __syncthreads();                                                                  \
  }

// ---------------- QKV GEMM: M=4096 x N=1536 x K=1024 ----------------
__global__ __launch_bounds__(256, 2) void gemm_qkv(const unsigned short* __restrict__ A,
                                                   const unsigned short* __restrict__ Bt,
                                                   const float2* __restrict__ scT,
                                                   unsigned short* __restrict__ Qh,
                                                   unsigned short* __restrict__ Kh,
                                                   unsigned short* __restrict__ Vt) {
  __shared__ __align__(16) unsigned short sm[2][2][128 * 64];   // 64 KiB
  const int tid = threadIdx.x;
  const int bid = blockIdx.x;
  const int swz = (bid & 7) * 48 + (bid >> 3);      // XCD-contiguous chunks
  const int nt = swz % 12, mt = swz / 12;
  const int m0 = mt * 128, n0 = nt * 128;

  const int lane = tid & 63, wid = tid >> 6;
  const int wr = wid >> 1, wc = wid & 1;            // wave quadrant (64x64)
  const int lgrp = lane >> 4, lmod = lane & 15;
  const int xorsel = (lmod & 7) << 4;
  const int arow = (wr * 64 + lmod) * 128;          // byte base of A-frag rows
  const int brow = (wc * 64 + lmod) * 128;

  const unsigned short* Ab = A + (size_t)m0 * 1024;
  const unsigned short* Bb = Bt + (size_t)n0 * 1024;

  f32x4 acc[4][4] = {};

  stage_tile(Ab, sm[0][0], tid);
  stage_tile(Bb, sm[0][1], tid);
  __syncthreads();

  for (int t = 0; t < 16; t += 2) {
    GEMM_STEP(0, 1, (size_t)(t + 1) * 64, true);
    GEMM_STEP(1, 0, (size_t)(t + 2) * 64, t < 14);
  }

  // ---------------- epilogue ----------------
  const int ncol0 = n0 + wc * 64;                   // aligned to one head
  if (ncol0 >= 1280) {
    // V: transposed store
    const int kvh = (ncol0 - 1280) >> 6;
#pragma unroll
    for (int mi = 0; mi < 4; ++mi)
#pragma unroll
      for (int ni = 0; ni < 4; ++ni) {
        int d = ni * 16 + lmod;
        int s = m0 + wr * 64 + mi * 16 + lgrp * 4;
        uint2 o;
        o.x = pack2bf(acc[mi][ni][0], acc[mi][ni][1]);
        o.y = pack2bf(acc[mi][ni][2], acc[mi][ni][3]);
        *(uint2*)&Vt[((size_t)(kvh * 64 + d)) * 4096 + s] = o;
      }
    return;
  }

  const float qscale = 0.18033688011112042f;   // 0.125 * log2(e)
  const bool isQ = (ncol0 < 1024);
  const int h = isQ ? (ncol0 >> 6) : ((ncol0 - 1024) >> 6);
  unsigned short* dstbase = isQ ? Qh : Kh;
  const bool evn = (lmod & 1) == 0;
#pragma unroll
  for (int mi = 0; mi < 4; ++mi)
#pragma unroll
    for (int ni = 0; ni < 4; ++ni) {
      int d = ni * 16 + lmod;
      int i = d >> 1;
#pragma unroll
      for (int r = 0; r < 4; ++r) {
        float v = acc[mi][ni][r];
        float pp = __shfl_xor(v, 1, 64);
        int row = m0 + wr * 64 + mi * 16 + lgrp * 4 + r;
        float2 sc = scT[(size_t)row * 32 + i];
        float e = evn ? v : pp, o = evn ? pp : v;
        float outv = evn ? (sc.y * e - sc.x * o) : (sc.x * e + sc.y * o);
        if (isQ) outv *= qscale;
        dstbase[((size_t)h * 4096 + row) * 64 + d] = f2bf(outv);
      }
    }
}

// ---------------- out-proj GEMM: M=4096 x N=1024 x K=1024, f32 out ----------------
__global__ __launch_bounds__(256, 2) void gemm_out(const unsigned short* __restrict__ A,
                                                   const unsigned short* __restrict__ Bt,
                                                   float* __restrict__ Cout) {
  __shared__ __align__(16) unsigned short sm[2][2][128 * 64];   // 64 KiB
  const int tid = threadIdx.x;
  const int bid = blockIdx.x;
  const int swz = (bid & 7) * 32 + (bid >> 3);
  const int nt = swz & 7, mt = swz >> 3;
  const int m0 = mt * 128, n0 = nt * 128;

  const int lane = tid & 63, wid = tid >> 6;
  const int wr = wid >> 1, wc = wid & 1;
  const int lgrp = lane >> 4, lmod = lane & 15;
  const int xorsel = (lmod & 7) << 4;
  const int arow = (wr * 64 + lmod) * 128;
  const int brow = (wc * 64 + lmod) * 128;

  const unsigned short* Ab = A + (size_t)m0 * 1024;
  const unsigned short* Bb = Bt + (size_t)n0 * 1024;

  f32x4 acc[4][4] = {};

  stage_tile(Ab, sm[0][0], tid);
  stage_tile(Bb, sm[0][1], tid);
  __syncthreads();

  for (int t = 0; t < 16; t += 2) {
    GEMM_STEP(0, 1, (size_t)(t + 1) * 64, true);
    GEMM_STEP(1, 0, (size_t)(t + 2) * 64, t < 14);
  }

#pragma unroll
  for (int mi = 0; mi < 4; ++mi)
#pragma unroll
    for (int ni = 0; ni < 4; ++ni)
#pragma unroll
      for (int r = 0; r < 4; ++r) {
        int row = m0 + wr * 64 + mi * 16 + lgrp * 4 + r;
        int col = n0 + wc * 64 + ni * 16 + lmod;
        Cout[(size_t)row * 1024 + col] = acc[mi][ni][r];
      }
}

// ---------------- Flash attention v5: V direct from global (no V LDS) --------------
// R3 showed LDS pipe ~90% busy (128KB reads + 32KB writes + 13M conflict-cy per
// dispatch). V fragments are read straight from Vt[d][s] (already PV layout):
// offloads 16KB write (8-way conflict) + 64KB read per block-tile to the VMEM/L1
// pipe. K stays in padded LDS. V frags double-buffered across the g-loop.
__global__ __launch_bounds__(256, 4) void attn5(const unsigned short* __restrict__ Qh,
                                                const unsigned short* __restrict__ Kh,
                                                const unsigned short* __restrict__ Vt,
                                                unsigned short* __restrict__ ctx) {
  __shared__ __align__(16) unsigned short Kls[128 * 68];   // [key][d], stride 68
  const int bx = blockIdx.x;
  const int head = bx & 15;
  const int qidx = bx >> 4;                         // 0..63
  const int qh = (qidx < 32) ? (63 - qidx) : (qidx - 32);  // pair-balanced
  const int kvh = head >> 2;
  const int tid = threadIdx.x;
  const int wave = tid >> 6, lane = tid & 63;
  const int lgrp = lane >> 4, lmod = lane & 15;
  const int qbase = qh * 64;
  const int ntile = qh >> 1;                        // last 128-key tile index

  const unsigned short* Kg = Kh + (size_t)kvh * 4096 * 64;
  const unsigned short* Vg = Vt + (size_t)kvh * 64 * 4096;
  // per-thread V fragment base: row d = dt*16 + lmod, col = kb + g*32 + lgrp*8
  const unsigned short* Vbase = Vg + (size_t)lmod * 4096 + lgrp * 8;

  const int qrow = qbase + wave * 16 + lmod;
  const unsigned short* Qg = Qh + ((size_t)head * 4096 + qrow) * 64;
  bf16x8 qf0 = __builtin_bit_cast(bf16x8, *(const u32x4*)&Qg[lgrp * 8]);
  bf16x8 qf1 = __builtin_bit_cast(bf16x8, *(const u32x4*)&Qg[32 + lgrp * 8]);

  const int kbase = (8 * (lmod >> 2) + (lmod & 3)) * 68 + lgrp * 8;

  f32x4 accO[4] = {};
  float m_i = -3e38f, l_i = 0.f;

  for (int kc = 0; kc <= ntile; ++kc) {
    const int kb = kc * 128;
    __syncthreads();
#pragma unroll
    for (int i = 0; i < 4; ++i) {
      int ii = tid + i * 256;
      int r = ii >> 3, sg = (ii & 7) * 8;
      u32x4 dK = *(const u32x4*)&Kg[(size_t)(kb + r) * 64 + sg];
      uint2* pd = (uint2*)&Kls[r * 68 + sg];
      pd[0] = make_uint2(dK[0], dK[1]);
      pd[1] = make_uint2(dK[2], dK[3]);
    }
    __syncthreads();

    f32x4 s[4][2];
    __builtin_amdgcn_s_setprio(1);
#pragma unroll
    for (int g = 0; g < 4; ++g)
#pragma unroll
      for (int t = 0; t < 2; ++t) {
        const unsigned short* ka = &Kls[kbase + (32 * g + 4 * t) * 68];
        uint2 a0 = *(const uint2*)&ka[0];
        uint2 a1 = *(const uint2*)&ka[4];
        uint2 b0 = *(const uint2*)&ka[32];
        uint2 b1 = *(const uint2*)&ka[36];
        u32x4 lo = {a0.x, a0.y, a1.x, a1.y};
        u32x4 hi = {b0.x, b0.y, b1.x, b1.y};
        bf16x8 alo = __builtin_bit_cast(bf16x8, lo);
        bf16x8 ahi = __builtin_bit_cast(bf16x8, hi);
        f32x4 z = {};
        z = __builtin_amdgcn_mfma_f32_16x16x32_bf16(alo, qf0, z, 0, 0, 0);
        z = __builtin_amdgcn_mfma_f32_16x16x32_bf16(ahi, qf1, z, 0, 0, 0);
        s[g][t] = z;
      }
    __builtin_amdgcn_s_setprio(0);

    // issue V fragment loads for g=0 now; latency hides under softmax VALU
    u32x4 vA[4], vB[4];
#pragma unroll
    for (int dt = 0; dt < 4; ++dt)
      vA[dt] = *(const u32x4*)&Vbase[(size_t)dt * 65536 + kb];

    if (kb + 127 > qbase + wave * 16) {
#pragma unroll
      for (int g = 0; g < 4; ++g)
#pragma unroll
        for (int t = 0; t < 2; ++t)
#pragma unroll
          for (int r = 0; r < 4; ++r) {
            int key = kb + 32 * g + 8 * lgrp + 4 * t + r;
            if (key > qrow) s[g][t][r] = -3e38f;
          }
    }

    {
      f32x4 v0 = s[0][0], v1 = s[0][1];
#pragma unroll
      for (int g = 1; g < 4; ++g)
#pragma unroll
        for (int r = 0; r < 4; ++r) {
          v0[r] = fmaxf(v0[r], s[g][0][r]);
          v1[r] = fmaxf(v1[r], s[g][1][r]);
        }
      float mx = fmaxf(fmaxf(fmaxf(v0[0], v0[1]), fmaxf(v0[2], v0[3])),
                       fmaxf(fmaxf(v1[0], v1[1]), fmaxf(v1[2], v1[3])));
      mx = fmaxf(mx, __shfl_xor(mx, 16, 64));
      mx = fmaxf(mx, __shfl_xor(mx, 32, 64));
      float mnew = fmaxf(m_i, mx);
      float alpha = __builtin_amdgcn_exp2f(m_i - mnew);
      m_i = mnew;
      f32x4 su = {};
#pragma unroll
      for (int g = 0; g < 4; ++g)
#pragma unroll
        for (int t = 0; t < 2; ++t)
#pragma unroll
          for (int r = 0; r < 4; ++r) {
            float ev = __builtin_amdgcn_exp2f(s[g][t][r] - mnew);
            s[g][t][r] = ev;
            su[r] += ev;
          }
      float rs = (su[0] + su[1]) + (su[2] + su[3]);
      rs += __shfl_xor(rs, 16, 64);
      rs += __shfl_xor(rs, 32, 64);
      l_i = l_i * alpha + rs;
#pragma unroll
      for (int dt = 0; dt < 4; ++dt)
#pragma unroll
        for (int r = 0; r < 4; ++r) accO[dt][r] *= alpha;
    }

    // ---- PV: V frags from global, double-buffered across g ----
#define PACK_P(g, pf)                                                      \
    {                                                                      \
      u32x4 pk;                                                            \
      pk[0] = packtr(s[g][0][0], s[g][0][1]);                              \
      pk[1] = packtr(s[g][0][2], s[g][0][3]);                              \
      pk[2] = packtr(s[g][1][0], s[g][1][1]);                              \
      pk[3] = packtr(s[g][1][2], s[g][1][3]);                              \
      pf = __builtin_bit_cast(bf16x8, pk);                                 \
    }
#define PV_G(vregs, pf)                                                    \
    _Pragma("unroll")                                                      \
    for (int dt = 0; dt < 4; ++dt) {                                       \
      bf16x8 vf = __builtin_bit_cast(bf16x8, vregs[dt]);                   \
      accO[dt] = __builtin_amdgcn_mfma_f32_16x16x32_bf16(vf, pf, accO[dt], 0, 0, 0); \
    }

    bf16x8 pf0, pf1, pf2, pf3;
    PACK_P(0, pf0);
    PACK_P(1, pf1);
    PACK_P(2, pf2);
    PACK_P(3, pf3);

#pragma unroll
    for (int dt = 0; dt < 4; ++dt)
      vB[dt] = *(const u32x4*)&Vbase[(size_t)dt * 65536 + kb + 32];
    __builtin_amdgcn_s_setprio(1);
    PV_G(vA, pf0);
#pragma unroll
    for (int dt = 0; dt < 4; ++dt)
      vA[dt] = *(const u32x4*)&Vbase[(size_t)dt * 65536 + kb + 64];
    PV_G(vB, pf1);
#pragma unroll
    for (int dt = 0; dt < 4; ++dt)
      vB[dt] = *(const u32x4*)&Vbase[(size_t)dt * 65536 + kb + 96];
    PV_G(vA, pf2);
    PV_G(vB, pf3);
    __builtin_amdgcn_s_setprio(0);
#undef PACK_P
#undef PV_G
  }

  {
    float inv = 1.f / l_i;
#pragma unroll
    for (int dt = 0; dt < 4; ++dt) {
      uint2 o;
      o.x = pack2bf(accO[dt][0] * inv, accO[dt][1] * inv);
      o.y = pack2bf(accO[dt][2] * inv, accO[dt][3] * inv);
      *(uint2*)&ctx[(size_t)qrow * 1024 + head * 64 + dt * 16 + lgrp * 4] = o;
    }
  }
}

extern "C" void kernel_launch(void* const* d_in, const int* in_sizes, int n_in,
                              void* d_out, int out_size, void* d_ws, size_t ws_size,
                              hipStream_t stream) {
  const float* x    = (const float*)d_in[0];
  const float* wq   = (const float*)d_in[3];
  const float* wk   = (const float*)d_in[4];
  const float* wv   = (const float*)d_in[5];
  const float* wo   = (const float*)d_in[6];
  const float* sinT = (const float*)d_in[7];
  const float* cosT = (const float*)d_in[8];

  unsigned short* ws    = (unsigned short*)d_ws;
  unsigned short* xb    = ws;                          // 4096*1024
  unsigned short* wtqkv = xb + 4096 * 1024;            // 1536*1024
  unsigned short* wot   = wtqkv + 1536 * 1024;         // 1024*1024
  unsigned short* Qh    = wot + 1024 * 1024;           // 16*4096*64
  unsigned short* Kh    = Qh + 16 * 4096 * 64;         // 4*4096*64
  unsigned short* Vt    = Kh + 4 * 4096 * 64;          // 4*64*4096
  unsigned short* ctx   = Vt + 4 * 64 * 4096;          // 4096*1024
  float2* scT           = (float2*)(ctx + 4096 * 1024);// 4096*32 float2
  float* out = (float*)d_out;

  prep<<<7168, 256, 0, stream>>>(x, wq, wk, wv, wo, sinT, cosT, xb, wtqkv, wot, scT);
  gemm_qkv<<<384, 256, 0, stream>>>(xb, wtqkv, scT, Qh, Kh, Vt);
  attn5<<<dim3(1024), 256, 0, stream>>>(Qh, Kh, Vt, ctx);
  gemm_out<<<256, 256, 0, stream>>>(ctx, wot, out);
}

// Round 5
// 216.203 us; speedup vs baseline: 1.4209x; 1.4209x over previous
//
#include <hip/hip_runtime.h>

typedef __bf16 bf16x8 __attribute__((ext_vector_type(8)));
typedef float f32x4 __attribute__((ext_vector_type(4)));
typedef unsigned int u32x4 __attribute__((ext_vector_type(4)));

typedef const void __attribute__((address_space(1)))* gas1;
typedef void __attribute__((address_space(3)))* las3;

__device__ __forceinline__ unsigned short f2bf(float f) {
  unsigned int u = __builtin_bit_cast(unsigned int, f);
  u += 0x7fffu + ((u >> 16) & 1u);   // RNE
  return (unsigned short)(u >> 16);
}
__device__ __forceinline__ float bf2f(unsigned short h) {
  unsigned int u = ((unsigned int)h) << 16;
  return __builtin_bit_cast(float, u);
}
__device__ __forceinline__ unsigned int pack2bf(float lo, float hi) {
  return (unsigned int)f2bf(lo) | ((unsigned int)f2bf(hi) << 16);
}
// truncating pack (P in [0,1])
__device__ __forceinline__ unsigned int packtr(float lo, float hi) {
  return __builtin_amdgcn_perm(__builtin_bit_cast(unsigned int, hi),
                               __builtin_bit_cast(unsigned int, lo), 0x07060302u);
}

// ---------------- fused prep: x->bf16 + 4 weight transposes + packed sin/cos ----------
__global__ __launch_bounds__(256) void prep(const float* __restrict__ x,
                                            const float* __restrict__ wq,
                                            const float* __restrict__ wk,
                                            const float* __restrict__ wv,
                                            const float* __restrict__ wo,
                                            const float* __restrict__ sinT,
                                            const float* __restrict__ cosT,
                                            unsigned short* __restrict__ xb,
                                            unsigned short* __restrict__ wtqkv,
                                            unsigned short* __restrict__ wot,
                                            float2* __restrict__ scT) {
  __shared__ float tile[32][33];
  const int b = blockIdx.x;
  const int tid = threadIdx.x;
  if (b < 4096) {
    int i = b * 256 + tid;
    float4 v = ((const float4*)x)[i];
    uint2 o;
    o.x = pack2bf(v.x, v.y);
    o.y = pack2bf(v.z, v.w);
    ((uint2*)xb)[i] = o;
    return;
  }
  if (b >= 6656) {
    int idx = (b - 6656) * 256 + tid;    // 131072 = 4096*32
    scT[idx] = make_float2(sinT[idx], cosT[idx]);
    return;
  }
  const float* src;
  unsigned short* dst;
  int R, C, t;
  if (b < 5120)      { t = b - 4096; src = wq; dst = wtqkv;               R = 1024; C = 1024; }
  else if (b < 5376) { t = b - 5120; src = wk; dst = wtqkv + 1024 * 1024; R = 1024; C = 256; }
  else if (b < 5632) { t = b - 5376; src = wv; dst = wtqkv + 1280 * 1024; R = 1024; C = 256; }
  else               { t = b - 5632; src = wo; dst = wot;                 R = 1024; C = 1024; }
  const int ntc = C >> 5;
  const int c0 = (t % ntc) * 32, r0 = (t / ntc) * 32;
  const int tx = tid & 31, ty = tid >> 5;
#pragma unroll
  for (int i = 0; i < 4; ++i)
    tile[ty + i * 8][tx] = src[(r0 + ty + i * 8) * C + c0 + tx];
  __syncthreads();
#pragma unroll
  for (int i = 0; i < 4; ++i)
    dst[(c0 + ty + i * 8) * R + r0 + tx] = f2bf(tile[tx][ty + i * 8]);
}

// ======================================================================
// 128x128-tile, 4-wave, BK=64, double-buffered GEMM core (unchanged).
// ======================================================================

__device__ __forceinline__ void stage_tile(const unsigned short* __restrict__ src,
                                           unsigned short* lds, int tid) {
  const int w = tid >> 6;            // wave id (0..3)
  const int l = tid & 63;
  const int rsub = l >> 3;           // 0..7 row within 8-row group
  const int cblk = l & 7;            // 0..7 16B block within row
#pragma unroll
  for (int i = 0; i < 4; ++i) {
    const int row = i * 32 + w * 8 + rsub;
    const int scol = (cblk ^ (row & 7)) * 8;   // pre-swizzled source column
    __builtin_amdgcn_global_load_lds((gas1)(const void*)&src[(size_t)row * 1024 + scol],
                                     (las3)(void*)&lds[(i * 32 + w * 8) * 64], 16, 0, 0);
  }
}

#define GEMM_STEP(CUR, NXT, KNEXT, DO_STAGE)                                          \
  {                                                                                   \
    if (DO_STAGE) {                                                                   \
      stage_tile(Ab + (KNEXT), sm[NXT][0], tid);                                      \
      stage_tile(Bb + (KNEXT), sm[NXT][1], tid);                                      \
    }                                                                                 \
    const char* As = (const char*)sm[CUR][0];                                         \
    const char* Bs = (const char*)sm[CUR][1];                                         \
    bf16x8 af[2][4], bfr[2][4];                                                       \
    _Pragma("unroll")                                                                 \
    for (int kk = 0; kk < 2; ++kk) {                                                  \
      const int co = (kk * 64 + lgrp * 16) ^ xorsel;                                  \
      _Pragma("unroll")                                                               \
      for (int mi = 0; mi < 4; ++mi)                                                  \
        af[kk][mi] = __builtin_bit_cast(bf16x8,                                       \
            *(const u32x4*)(As + arow + mi * 2048 + co));                             \
      _Pragma("unroll")                                                               \
      for (int ni = 0; ni < 4; ++ni)                                                  \
        bfr[kk][ni] = __builtin_bit_cast(bf16x8,                                      \
            *(const u32x4*)(Bs + brow + ni * 2048 + co));                             \
    }                                                                                 \
    _Pragma("unroll")                                                                 \
    for (int kk = 0; kk < 2; ++kk)                                                    \
      _Pragma("unroll")                                                               \
      for (int mi = 0; mi < 4; ++mi)                                                  \
        _Pragma("unroll")                                                             \
        for (int ni = 0; ni < 4; ++ni)                                                \
          acc[mi][ni] = __builtin_amdgcn_mfma_f32_16x16x32_bf16(af[kk][mi],           \
                            bfr[kk][ni], acc[mi][ni], 0, 0, 0);                       \
    __syncthreads();                                                                  \
  }

// ---------------- QKV GEMM: M=4096 x N=1536 x K=1024 ----------------
__global__ __launch_bounds__(256, 2) void gemm_qkv(const unsigned short* __restrict__ A,
                                                   const unsigned short* __restrict__ Bt,
                                                   const float2* __restrict__ scT,
                                                   unsigned short* __restrict__ Qh,
                                                   unsigned short* __restrict__ Kh,
                                                   unsigned short* __restrict__ Vt) {
  __shared__ __align__(16) unsigned short sm[2][2][128 * 64];   // 64 KiB
  const int tid = threadIdx.x;
  const int bid = blockIdx.x;
  const int swz = (bid & 7) * 48 + (bid >> 3);      // XCD-contiguous chunks
  const int nt = swz % 12, mt = swz / 12;
  const int m0 = mt * 128, n0 = nt * 128;

  const int lane = tid & 63, wid = tid >> 6;
  const int wr = wid >> 1, wc = wid & 1;            // wave quadrant (64x64)
  const int lgrp = lane >> 4, lmod = lane & 15;
  const int xorsel = (lmod & 7) << 4;
  const int arow = (wr * 64 + lmod) * 128;          // byte base of A-frag rows
  const int brow = (wc * 64 + lmod) * 128;

  const unsigned short* Ab = A + (size_t)m0 * 1024;
  const unsigned short* Bb = Bt + (size_t)n0 * 1024;

  f32x4 acc[4][4] = {};

  stage_tile(Ab, sm[0][0], tid);
  stage_tile(Bb, sm[0][1], tid);
  __syncthreads();

  for (int t = 0; t < 16; t += 2) {
    GEMM_STEP(0, 1, (size_t)(t + 1) * 64, true);
    GEMM_STEP(1, 0, (size_t)(t + 2) * 64, t < 14);
  }

  // ---------------- epilogue ----------------
  const int ncol0 = n0 + wc * 64;                   // aligned to one head
  if (ncol0 >= 1280) {
    // V: transposed store
    const int kvh = (ncol0 - 1280) >> 6;
#pragma unroll
    for (int mi = 0; mi < 4; ++mi)
#pragma unroll
      for (int ni = 0; ni < 4; ++ni) {
        int d = ni * 16 + lmod;
        int s = m0 + wr * 64 + mi * 16 + lgrp * 4;
        uint2 o;
        o.x = pack2bf(acc[mi][ni][0], acc[mi][ni][1]);
        o.y = pack2bf(acc[mi][ni][2], acc[mi][ni][3]);
        *(uint2*)&Vt[((size_t)(kvh * 64 + d)) * 4096 + s] = o;
      }
    return;
  }

  const float qscale = 0.18033688011112042f;   // 0.125 * log2(e)
  const bool isQ = (ncol0 < 1024);
  const int h = isQ ? (ncol0 >> 6) : ((ncol0 - 1024) >> 6);
  unsigned short* dstbase = isQ ? Qh : Kh;
  const bool evn = (lmod & 1) == 0;
#pragma unroll
  for (int mi = 0; mi < 4; ++mi)
#pragma unroll
    for (int ni = 0; ni < 4; ++ni) {
      int d = ni * 16 + lmod;
      int i = d >> 1;
#pragma unroll
      for (int r = 0; r < 4; ++r) {
        float v = acc[mi][ni][r];
        float pp = __shfl_xor(v, 1, 64);
        int row = m0 + wr * 64 + mi * 16 + lgrp * 4 + r;
        float2 sc = scT[(size_t)row * 32 + i];
        float e = evn ? v : pp, o = evn ? pp : v;
        float outv = evn ? (sc.y * e - sc.x * o) : (sc.x * e + sc.y * o);
        if (isQ) outv *= qscale;
        dstbase[((size_t)h * 4096 + row) * 64 + d] = f2bf(outv);
      }
    }
}

// ---------------- out-proj GEMM: M=4096 x N=1024 x K=1024, f32 out ----------------
__global__ __launch_bounds__(256, 2) void gemm_out(const unsigned short* __restrict__ A,
                                                   const unsigned short* __restrict__ Bt,
                                                   float* __restrict__ Cout) {
  __shared__ __align__(16) unsigned short sm[2][2][128 * 64];   // 64 KiB
  const int tid = threadIdx.x;
  const int bid = blockIdx.x;
  const int swz = (bid & 7) * 32 + (bid >> 3);
  const int nt = swz & 7, mt = swz >> 3;
  const int m0 = mt * 128, n0 = nt * 128;

  const int lane = tid & 63, wid = tid >> 6;
  const int wr = wid >> 1, wc = wid & 1;
  const int lgrp = lane >> 4, lmod = lane & 15;
  const int xorsel = (lmod & 7) << 4;
  const int arow = (wr * 64 + lmod) * 128;
  const int brow = (wc * 64 + lmod) * 128;

  const unsigned short* Ab = A + (size_t)m0 * 1024;
  const unsigned short* Bb = Bt + (size_t)n0 * 1024;

  f32x4 acc[4][4] = {};

  stage_tile(Ab, sm[0][0], tid);
  stage_tile(Bb, sm[0][1], tid);
  __syncthreads();

  for (int t = 0; t < 16; t += 2) {
    GEMM_STEP(0, 1, (size_t)(t + 1) * 64, true);
    GEMM_STEP(1, 0, (size_t)(t + 2) * 64, t < 14);
  }

#pragma unroll
  for (int mi = 0; mi < 4; ++mi)
#pragma unroll
    for (int ni = 0; ni < 4; ++ni)
#pragma unroll
      for (int r = 0; r < 4; ++r) {
        int row = m0 + wr * 64 + mi * 16 + lgrp * 4 + r;
        int col = n0 + wc * 64 + ni * 16 + lmod;
        Cout[(size_t)row * 1024 + col] = acc[mi][ni][r];
      }
}

// ---------------- Flash attention v6: conflict-free XOR-swizzled LDS + async stage ----
// K: linear [128][64] via global_load_lds, 16B-block XOR (blk ^= row&7) applied on
//    SOURCE address + READ address (both-sides involution). A-row permutation
//    key = 32g + t + 2*lmod spreads row parity so b128 frag reads hit 8 lanes/quad.
// V: linear [64][128] via global_load_lds, blk ^= d&15; frag read (4g+lgrp)^lmod.
// All LDS reads/writes conflict-free by bank arithmetic; staging is async (vmcnt
// drain lands at the pre-compute barrier only).
__global__ __launch_bounds__(256, 4) void attn6(const unsigned short* __restrict__ Qh,
                                                const unsigned short* __restrict__ Kh,
                                                const unsigned short* __restrict__ Vt,
                                                unsigned short* __restrict__ ctx) {
  __shared__ __align__(16) unsigned short Kls[128 * 64];   // 16 KiB, swizzled linear
  __shared__ __align__(16) unsigned short Vls[64 * 128];   // 16 KiB, swizzled linear
  const int bx = blockIdx.x;
  const int head = bx & 15;
  const int qidx = bx >> 4;                         // 0..63
  const int qh = (qidx < 32) ? (63 - qidx) : (qidx - 32);  // pair-balanced
  const int kvh = head >> 2;
  const int tid = threadIdx.x;
  const int wave = tid >> 6, lane = tid & 63;
  const int lgrp = lane >> 4, lmod = lane & 15;
  const int qbase = qh * 64;
  const int ntile = qh >> 1;                        // last 128-key tile index

  const unsigned short* Kg = Kh + (size_t)kvh * 4096 * 64;
  const unsigned short* Vg = Vt + (size_t)kvh * 64 * 4096;

  const int qrow = qbase + wave * 16 + lmod;
  const unsigned short* Qg = Qh + ((size_t)head * 4096 + qrow) * 64;
  bf16x8 qf0 = __builtin_bit_cast(bf16x8, *(const u32x4*)&Qg[lgrp * 8]);
  bf16x8 qf1 = __builtin_bit_cast(bf16x8, *(const u32x4*)&Qg[32 + lgrp * 8]);

  f32x4 accO[4] = {};
  float m_i = -3e38f, l_i = 0.f;

  for (int kc = 0; kc <= ntile; ++kc) {
    const int kb = kc * 128;
    __syncthreads();               // prior tile's LDS reads complete
    // ---- async stage K ([128][64], blk ^= row&7) ----
#pragma unroll
    for (int i = 0; i < 4; ++i) {
      int ii = tid + i * 256;
      int r = ii >> 3, b = ii & 7;
      __builtin_amdgcn_global_load_lds(
          (gas1)(const void*)&Kg[(size_t)(kb + r) * 64 + ((b ^ (r & 7)) * 8)],
          (las3)(void*)&Kls[(size_t)ii * 8], 16, 0, 0);
    }
    // ---- async stage V ([64][128], blk ^= d&15) ----
#pragma unroll
    for (int i = 0; i < 4; ++i) {
      int ii = tid + i * 256;
      int d = ii >> 4, b = ii & 15;
      __builtin_amdgcn_global_load_lds(
          (gas1)(const void*)&Vg[(size_t)d * 4096 + kb + ((b ^ (d & 15)) * 8)],
          (las3)(void*)&Vls[(size_t)ii * 8], 16, 0, 0);
    }
    __syncthreads();               // implicit vmcnt(0): staged data visible

    f32x4 s[4][2];
    __builtin_amdgcn_s_setprio(1);
#pragma unroll
    for (int g = 0; g < 4; ++g)
#pragma unroll
      for (int t = 0; t < 2; ++t) {
        const int row = 32 * g + t + 2 * lmod;     // key - kb for this lane's A-row
        bf16x8 alo = __builtin_bit_cast(bf16x8,
            *(const u32x4*)&Kls[(size_t)row * 64 + ((lgrp ^ (row & 7)) * 8)]);
        bf16x8 ahi = __builtin_bit_cast(bf16x8,
            *(const u32x4*)&Kls[(size_t)row * 64 + (((4 + lgrp) ^ (row & 7)) * 8)]);
        f32x4 z = {};
        z = __builtin_amdgcn_mfma_f32_16x16x32_bf16(alo, qf0, z, 0, 0, 0);
        z = __builtin_amdgcn_mfma_f32_16x16x32_bf16(ahi, qf1, z, 0, 0, 0);
        s[g][t] = z;
      }
    __builtin_amdgcn_s_setprio(0);

    if (kb + 127 > qbase + wave * 16) {
#pragma unroll
      for (int g = 0; g < 4; ++g)
#pragma unroll
        for (int t = 0; t < 2; ++t)
#pragma unroll
          for (int r = 0; r < 4; ++r) {
            int key = kb + 32 * g + 8 * lgrp + 2 * r + t;   // new row permutation
            if (key > qrow) s[g][t][r] = -3e38f;
          }
    }

    {
      f32x4 v0 = s[0][0], v1 = s[0][1];
#pragma unroll
      for (int g = 1; g < 4; ++g)
#pragma unroll
        for (int r = 0; r < 4; ++r) {
          v0[r] = fmaxf(v0[r], s[g][0][r]);
          v1[r] = fmaxf(v1[r], s[g][1][r]);
        }
      float mx = fmaxf(fmaxf(fmaxf(v0[0], v0[1]), fmaxf(v0[2], v0[3])),
                       fmaxf(fmaxf(v1[0], v1[1]), fmaxf(v1[2], v1[3])));
      mx = fmaxf(mx, __shfl_xor(mx, 16, 64));
      mx = fmaxf(mx, __shfl_xor(mx, 32, 64));
      float mnew = fmaxf(m_i, mx);
      float alpha = __builtin_amdgcn_exp2f(m_i - mnew);
      m_i = mnew;
      f32x4 su = {};
#pragma unroll
      for (int g = 0; g < 4; ++g)
#pragma unroll
        for (int t = 0; t < 2; ++t)
#pragma unroll
          for (int r = 0; r < 4; ++r) {
            float ev = __builtin_amdgcn_exp2f(s[g][t][r] - mnew);
            s[g][t][r] = ev;
            su[r] += ev;
          }
      float rs = (su[0] + su[1]) + (su[2] + su[3]);
      rs += __shfl_xor(rs, 16, 64);
      rs += __shfl_xor(rs, 32, 64);
      l_i = l_i * alpha + rs;
#pragma unroll
      for (int dt = 0; dt < 4; ++dt)
#pragma unroll
        for (int r = 0; r < 4; ++r) accO[dt][r] *= alpha;
    }

    __builtin_amdgcn_s_setprio(1);
#pragma unroll
    for (int g = 0; g < 4; ++g) {
      // P element j (k = 8*lgrp + j) must be key 32g+8*lgrp+j = (t = j&1, r = j>>1)
      u32x4 pk;
      pk[0] = packtr(s[g][0][0], s[g][1][0]);
      pk[1] = packtr(s[g][0][1], s[g][1][1]);
      pk[2] = packtr(s[g][0][2], s[g][1][2]);
      pk[3] = packtr(s[g][0][3], s[g][1][3]);
      bf16x8 pf = __builtin_bit_cast(bf16x8, pk);
#pragma unroll
      for (int dt = 0; dt < 4; ++dt) {
        const int d = dt * 16 + lmod;
        bf16x8 vf = __builtin_bit_cast(bf16x8,
            *(const u32x4*)&Vls[(size_t)d * 128 + (((4 * g + lgrp) ^ lmod) * 8)]);
        accO[dt] = __builtin_amdgcn_mfma_f32_16x16x32_bf16(vf, pf, accO[dt], 0, 0, 0);
      }
    }
    __builtin_amdgcn_s_setprio(0);
  }

  {
    float inv = 1.f / l_i;
#pragma unroll
    for (int dt = 0; dt < 4; ++dt) {
      uint2 o;
      o.x = pack2bf(accO[dt][0] * inv, accO[dt][1] * inv);
      o.y = pack2bf(accO[dt][2] * inv, accO[dt][3] * inv);
      *(uint2*)&ctx[(size_t)qrow * 1024 + head * 64 + dt * 16 + lgrp * 4] = o;
    }
  }
}

extern "C" void kernel_launch(void* const* d_in, const int* in_sizes, int n_in,
                              void* d_out, int out_size, void* d_ws, size_t ws_size,
                              hipStream_t stream) {
  const float* x    = (const float*)d_in[0];
  const float* wq   = (const float*)d_in[3];
  const float* wk   = (const float*)d_in[4];
  const float* wv   = (const float*)d_in[5];
  const float* wo   = (const float*)d_in[6];
  const float* sinT = (const float*)d_in[7];
  const float* cosT = (const float*)d_in[8];

  unsigned short* ws    = (unsigned short*)d_ws;
  unsigned short* xb    = ws;                          // 4096*1024
  unsigned short* wtqkv = xb + 4096 * 1024;            // 1536*1024
  unsigned short* wot   = wtqkv + 1536 * 1024;         // 1024*1024
  unsigned short* Qh    = wot + 1024 * 1024;           // 16*4096*64
  unsigned short* Kh    = Qh + 16 * 4096 * 64;         // 4*4096*64
  unsigned short* Vt    = Kh + 4 * 4096 * 64;          // 4*64*4096
  unsigned short* ctx   = Vt + 4 * 64 * 4096;          // 4096*1024
  float2* scT           = (float2*)(ctx + 4096 * 1024);// 4096*32 float2
  float* out = (float*)d_out;

  prep<<<7168, 256, 0, stream>>>(x, wq, wk, wv, wo, sinT, cosT, xb, wtqkv, wot, scT);
  gemm_qkv<<<384, 256, 0, stream>>>(xb, wtqkv, scT, Qh, Kh, Vt);
  attn6<<<dim3(1024), 256, 0, stream>>>(Qh, Kh, Vt, ctx);
  gemm_out<<<256, 256, 0, stream>>>(ctx, wot, out);
}